// Round 10
// baseline (333.499 us; speedup 1.0000x reference)
//
#include <hip/hip_runtime.h>
#include <math.h>

#ifndef M_PI
#define M_PI 3.14159265358979323846
#endif

#define GP     130
#define PAD    27
#define KBIAS  90.5f     // 63.5 + PAD
#define SMIR   181.0f    // 2*KBIAS
#define NSLOT  182
#define RSD    184       // dwords per row
#define NROWS  34        // 8 groups x 4 rows + special rows 0,64
#define ISTR   325       // inbox stride (floats) per w'

// One block per (c,hh), 1024 threads, 4 reps/thread (rep quarter [0,64)^2).
// D4 symmetry: u_a(Q) feeds rows {a,64-a,a+64,128-a} at pixels
// {Q, swapQ, rQ, MQ}; rot-accs R[4][4] + mirror-accs S[4][4] (32 floats ->
// fits arch VGPRs, no AGPR round-trips); S folded via LDS inbox exchange.
// Rows = f16 (p_i,p_{i+1}); v_dot2_f32_f16. a=32 orbit {32,32,96,96}
// degenerates: rows stored HALVED so double accumulation = exact single.
__global__ __launch_bounds__(1024, 4)
void fbp_fused(const float* __restrict__ F, float* __restrict__ out) {
    __shared__ __align__(16) unsigned s_rows[NROWS * RSD]; // 25024 B (+overlays)
    __shared__ float s_g[16][GP];
    __shared__ float s_h[128];
    __shared__ float s_cs[34];
    __shared__ float s_sn[34];

    float* s_cos = (float*)s_rows;          // [128]    phase-0 overlay
    float* s_raw = (float*)s_rows + 128;    // [16*129] phase-0 overlay
    float* inbox = (float*)s_rows;          // exchange overlay (s_rows dead)

    const int t   = threadIdx.x;
    const int blk = blockIdx.x;             // 0..1023
    const int hh  = blk & 127;
    const int c   = blk >> 7;

    // ---- stage 16 feature rows + tables ----
    const float* Fb = F + (((size_t)c * 128 + hh) * 128);
    #pragma unroll
    for (int e = 0; e < 2; ++e) {
        int idx = t + 1024 * e;
        int s = idx >> 7, m = idx & 127;
        s_raw[s * 129 + m] = Fb[(size_t)s * 131072 + m];
    }
    if (t < 128) s_cos[t] = cosf((float)t * (float)(M_PI / 64.0));
    if (t < 34) {
        float th = (float)t * (float)(M_PI / 128.0);
        s_cs[t] = cosf(th);
        s_sn[t] = sinf(th);
    }
    __syncthreads();

    // ---- ramp taps ----
    if (t < 128) {
        float sum = (t & 1) ? -64.f : 64.f;
        #pragma unroll
        for (int j = 1; j <= 63; ++j)
            sum = fmaf(2.f * (float)j, s_cos[(j * t) & 127], sum);
        s_h[t] = sum * (1.f / 16384.f);
    }
    __syncthreads();

    // ---- circular conv -> filtered slice rows s_g ----
    {
        const int s  = t >> 6;              // slice = wave id (uniform)
        const int n0 = t & 63;
        float fa[2] = {0.f, 0.f};
        const float* rawr = &s_raw[s * 129];
        for (int m = 0; m < 128; ++m) {
            float rm = rawr[m];
            int hb = (n0 - m) & 127;
            fa[0] = fmaf(rm, s_h[hb], fa[0]);
            fa[1] = fmaf(rm, s_h[(hb + 64) & 127], fa[1]);
        }
        s_g[s][n0]      = fa[0];
        s_g[s][n0 + 64] = fa[1];
    }

    // ---- backprojection ----
    const int   l  = t & 63;                // Y of rep pixel
    const int   w  = t >> 6;                // rep X0 = w*4 + m, m=0..3
    const float yl = (float)l - 63.5f;

    float R[4][4], S[4][4];
    #pragma unroll
    for (int m = 0; m < 4; ++m)
        #pragma unroll
        for (int k = 0; k < 4; ++k) { R[m][k] = 0.f; S[m][k] = 0.f; }

    #pragma unroll 1
    for (int ch = 0; ch < 4; ++ch) {
        __syncthreads();   // prev gather done / conv done; s_rows writable
        // build 32 rows: group g rows {a,64-a,a+64,128-a} at slots 4g+j
        {
            const int r_id   = t >> 5;      // 0..31
            const int lane32 = t & 31;
            const int g = r_id >> 2, j = r_id & 3;
            const int a = ch * 8 + g + 1;
            const int row = (j == 0) ? a : (j == 1) ? 64 - a
                          : (j == 2) ? a + 64 : 128 - a;
            const int i0 = row >> 3;
            const int i1 = (i0 + 1) & 15;
            const float w_ = (float)(row & 7) * 0.125f;
            const float hs = (a == 32) ? 0.5f : 1.0f;  // degenerate-orbit fix
            const float* g0r = s_g[i0];
            const float* g1r = s_g[i1];
            unsigned* rr = &s_rows[r_id * RSD];
            #pragma unroll
            for (int qq = 0; qq < 6; ++qq) {
                int p = lane32 + 32 * qq;
                if (p < NSLOT) {
                    int ix = p - PAD;
                    float v0 = 0.f, v1 = 0.f;
                    if ((unsigned)ix < 128u)
                        v0 = fmaf(w_, g1r[ix] - g0r[ix], g0r[ix]);
                    int iy = ix + 1;
                    if ((unsigned)iy < 128u)
                        v1 = fmaf(w_, g1r[iy] - g0r[iy], g0r[iy]);
                    rr[p] = __builtin_bit_cast(unsigned,
                        __builtin_amdgcn_cvt_pkrtz(v0 * hs, v1 * hs));
                }
            }
        }
        if (ch == 0 && t < 64) {            // special rows 0, 64 at slots 32,33
            const int r2 = t >> 5;          // 0 or 1
            const int lane32 = t & 31;
            const int i0 = (r2 * 64) >> 3;
            const float* g0r = s_g[i0];
            unsigned* rr = &s_rows[(32 + r2) * RSD];
            #pragma unroll
            for (int qq = 0; qq < 6; ++qq) {
                int p = lane32 + 32 * qq;
                if (p < NSLOT) {
                    int ix = p - PAD;
                    float v0 = ((unsigned)ix < 128u) ? g0r[ix] : 0.f;
                    int iy = ix + 1;
                    float v1 = ((unsigned)iy < 128u) ? g0r[iy] : 0.f;
                    rr[p] = __builtin_bit_cast(unsigned,
                        __builtin_amdgcn_cvt_pkrtz(v0, v1));
                }
            }
        }
        __syncthreads();

        #define SAMPLE4(U, RA, RB, SA, SB) do {                               \
            int   ii = (int)(U);                                              \
            float fr = __builtin_amdgcn_fractf(U);                            \
            unsigned wt = __builtin_bit_cast(unsigned,                        \
                __builtin_amdgcn_cvt_pkrtz(1.f - fr, fr));                    \
            const unsigned* pp = rowp + ii;                                   \
            unsigned w0 = pp[0];                                              \
            unsigned w1 = pp[RSD];                                            \
            unsigned w2 = pp[2 * RSD];                                        \
            unsigned w3 = pp[3 * RSD];                                        \
            asm("v_dot2_f32_f16 %0, %1, %2, %0" : "+v"(RA) : "v"(wt), "v"(w0));\
            asm("v_dot2_f32_f16 %0, %1, %2, %0" : "+v"(RB) : "v"(wt), "v"(w2));\
            asm("v_dot2_f32_f16 %0, %1, %2, %0" : "+v"(SA) : "v"(wt), "v"(w3));\
            asm("v_dot2_f32_f16 %0, %1, %2, %0" : "+v"(SB) : "v"(wt), "v"(w1));\
        } while (0)

        #pragma unroll 1
        for (int g = 0; g < 8; ++g) {
            const int a = ch * 8 + g + 1;
            const float cs = s_cs[a];
            const float sn = s_sn[a];
            const float ay = fmaf(yl, sn, KBIAS);
            const float by = fmaf(yl, -cs, KBIAS);
            const unsigned* rowp = &s_rows[(4 * g) * RSD];
            #pragma unroll
            for (int m = 0; m < 4; ++m) {
                const float xr = (float)(w * 4 + m) - 63.5f;
                float uA = fmaf(xr, cs, ay);
                float uB = fmaf(xr, sn, by);
                float uC = SMIR - uA;
                float uD = SMIR - uB;
                SAMPLE4(uA, R[m][0], R[m][1], S[m][0], S[m][3]);
                SAMPLE4(uB, R[m][1], R[m][2], S[m][3], S[m][2]);
                SAMPLE4(uC, R[m][2], R[m][3], S[m][2], S[m][1]);
                SAMPLE4(uD, R[m][3], R[m][0], S[m][1], S[m][0]);
            }
        }

        if (ch == 0) {                      // special group: rows 0 (slot32), 64 (slot33)
            const float by = fmaf(yl, -1.f, KBIAS);
            const unsigned* rowp = &s_rows[32 * RSD];
            #define SAMPLE2(U, RA, RB) do {                                   \
                int   ii = (int)(U);                                          \
                float fr = __builtin_amdgcn_fractf(U);                        \
                unsigned wt = __builtin_bit_cast(unsigned,                    \
                    __builtin_amdgcn_cvt_pkrtz(1.f - fr, fr));                \
                const unsigned* pp = rowp + ii;                               \
                unsigned w0 = pp[0];                                          \
                unsigned w1 = pp[RSD];                                        \
                asm("v_dot2_f32_f16 %0, %1, %2, %0" : "+v"(RA) : "v"(wt), "v"(w0));\
                asm("v_dot2_f32_f16 %0, %1, %2, %0" : "+v"(RB) : "v"(wt), "v"(w1));\
            } while (0)
            #pragma unroll
            for (int m = 0; m < 4; ++m) {
                const float xr = (float)(w * 4 + m) - 63.5f;
                float uA = xr + KBIAS;
                float uB = by;
                float uC = SMIR - uA;
                float uD = SMIR - uB;
                SAMPLE2(uA, R[m][0], R[m][1]);
                SAMPLE2(uB, R[m][1], R[m][2]);
                SAMPLE2(uC, R[m][2], R[m][3]);
                SAMPLE2(uD, R[m][3], R[m][0]);
            }
            #undef SAMPLE2
        }
        #undef SAMPLE4
    }

    // ---- fold mirror accs into owners: 4 LDS exchange rounds ----
    // S[m][k] = partial for pixel r^k(M Q_m), rep (l, X0m); owner thread
    // t' = (l>>2)*64 + X0m with m' = l&3. inbox[w'][l'][m'] stride ISTR.
    #pragma unroll
    for (int k = 0; k < 4; ++k) {
        __syncthreads();                    // prior reads (or gather) done
        #pragma unroll
        for (int m = 0; m < 4; ++m)
            inbox[(l >> 2) * ISTR + (w * 4 + m) * 5 + (l & 3)] = S[m][k];
        __syncthreads();
        #pragma unroll
        for (int m = 0; m < 4; ++m)
            R[m][(k + 1) & 3] += inbox[w * ISTR + l * 5 + m];
    }

    // ---- write out: pixels r^k(Q_m), Q_m = (X0, l) ----
    float* ob = out + (size_t)blk * 16384;
    const float sc = (float)(M_PI / 128.0);
    #pragma unroll
    for (int m = 0; m < 4; ++m) {
        const int X0 = w * 4 + m;
        ob[X0 * 128 + l]                 = R[m][0] * sc;
        ob[(127 - l) * 128 + X0]         = R[m][1] * sc;
        ob[(127 - X0) * 128 + (127 - l)] = R[m][2] * sc;
        ob[l * 128 + (127 - X0)]         = R[m][3] * sc;
    }
}

extern "C" void kernel_launch(void* const* d_in, const int* in_sizes, int n_in,
                              void* d_out, int out_size, void* d_ws, size_t ws_size,
                              hipStream_t stream) {
    const float* F = (const float*)d_in[0];
    float* out = (float*)d_out;
    fbp_fused<<<1024, 1024, 0, stream>>>(F, out);
}

// Round 11
// 281.880 us; speedup vs baseline: 1.1831x; 1.1831x over previous
//
#include <hip/hip_runtime.h>
#include <math.h>

#ifndef M_PI
#define M_PI 3.14159265358979323846
#endif

#define GP     130
#define PAD    27
#define KBIAS  90.5f     // 63.5 + PAD
#define SMIR   181.0f    // 2*KBIAS
#define NENT   182       // entries p = 0..181 (ii in [0,180], taps ii, ii+1)
#define GSTR   184       // group stride in 8B slots
#define ISTR   325       // inbox stride (floats) per w'

// One block per (c,hh), 1024 threads, 4 reps/thread (quarter [0,64)^2).
// D4 symmetry; rows stored GROUP-TRANSPOSED: slot i of group a holds f16x4
// (row_a[i], row_{64-a}[i], row_{64+a}[i], row_{128-a}[i]) -> one ds_read_b64
// pair (ii, ii+1 via offset:8) serves ALL FOUR rows' lerp taps (0.5 LDS
// instr/contrib). Accumulate with v_fma_mix_f32 (f32 weights, f16 values).
// a=32 orbit degenerates {32,32,96,96}: stored halved (two half-paths sum).
__global__ __launch_bounds__(1024, 8)
void fbp_fused(const float* __restrict__ F, float* __restrict__ out) {
    __shared__ __align__(16) unsigned s_rows[32 * GSTR * 2 + GSTR]; // 47.8 KB
    __shared__ float s_g[16][GP];
    __shared__ float s_h[128];
    __shared__ float s_cs[34];
    __shared__ float s_sn[34];

    float* s_cos = (float*)s_rows;          // [128]    phase-0 overlay
    float* s_raw = (float*)s_rows + 128;    // [16*129] phase-0 overlay
    float* inbox = (float*)s_rows;          // exchange overlay (rows dead)
    unsigned* s_sp = &s_rows[32 * GSTR * 2]; // special rows {0,64}, 4B slots

    const int t   = threadIdx.x;
    const int blk = blockIdx.x;             // 0..1023
    const int hh  = blk & 127;
    const int c   = blk >> 7;

    // ---- stage 16 feature rows + tables ----
    const float* Fb = F + (((size_t)c * 128 + hh) * 128);
    #pragma unroll
    for (int e = 0; e < 2; ++e) {
        int idx = t + 1024 * e;
        int s = idx >> 7, m = idx & 127;
        s_raw[s * 129 + m] = Fb[(size_t)s * 131072 + m];
    }
    if (t < 128) s_cos[t] = cosf((float)t * (float)(M_PI / 64.0));
    if (t < 34) {
        float th = (float)t * (float)(M_PI / 128.0);
        s_cs[t] = cosf(th);
        s_sn[t] = sinf(th);
    }
    __syncthreads();

    // ---- ramp taps ----
    if (t < 128) {
        float sum = (t & 1) ? -64.f : 64.f;
        #pragma unroll
        for (int j = 1; j <= 63; ++j)
            sum = fmaf(2.f * (float)j, s_cos[(j * t) & 127], sum);
        s_h[t] = sum * (1.f / 16384.f);
    }
    __syncthreads();

    // ---- circular conv -> filtered slice rows s_g ----
    {
        const int s  = t >> 6;
        const int n0 = t & 63;
        float fa[2] = {0.f, 0.f};
        const float* rawr = &s_raw[s * 129];
        for (int m = 0; m < 128; ++m) {
            float rm = rawr[m];
            int hb = (n0 - m) & 127;
            fa[0] = fmaf(rm, s_h[hb], fa[0]);
            fa[1] = fmaf(rm, s_h[(hb + 64) & 127], fa[1]);
        }
        s_g[s][n0]      = fa[0];
        s_g[s][n0 + 64] = fa[1];
    }
    __syncthreads();   // s_g ready; s_raw/s_cos dead -> s_rows writable

    // ---- build ALL 32 transposed groups + special pair ----
    {
        // 32*182 = 5824 slot-tasks
        #pragma unroll
        for (int e = 0; e < 6; ++e) {
            int task = t + 1024 * e;
            if (task < 32 * NENT) {
                int gi = task / NENT;       // 0..31 -> a = gi+1
                int p  = task - gi * NENT;  // 0..181
                int a  = gi + 1;
                const float hs = (a == 32) ? 0.5f : 1.0f;
                int ix = p - PAD;
                float v[4];
                #pragma unroll
                for (int j = 0; j < 4; ++j) {
                    int row = (j == 0) ? a : (j == 1) ? 64 - a
                            : (j == 2) ? 64 + a : 128 - a;
                    int i0 = row >> 3, i1 = (i0 + 1) & 15;
                    float w_ = (float)(row & 7) * 0.125f;
                    float val = 0.f;
                    if ((unsigned)ix < 128u)
                        val = fmaf(w_, s_g[i1][ix] - s_g[i0][ix], s_g[i0][ix]) * hs;
                    v[j] = val;
                }
                uint2* slot = (uint2*)&s_rows[(gi * GSTR + p) * 2];
                uint2 pk;
                pk.x = __builtin_bit_cast(unsigned, __builtin_amdgcn_cvt_pkrtz(v[0], v[1]));
                pk.y = __builtin_bit_cast(unsigned, __builtin_amdgcn_cvt_pkrtz(v[2], v[3]));
                *slot = pk;
            }
        }
        if (t < NENT) {                     // special rows 0 (lo), 64 (hi)
            int ix = t - PAD;
            float v0 = ((unsigned)ix < 128u) ? s_g[0][ix] : 0.f;
            float v1 = ((unsigned)ix < 128u) ? s_g[8][ix] : 0.f;
            s_sp[t] = __builtin_bit_cast(unsigned, __builtin_amdgcn_cvt_pkrtz(v0, v1));
        }
    }
    __syncthreads();

    // ---- backprojection gather (one uninterrupted pass, 128 angles) ----
    const int   l  = t & 63;
    const int   w  = t >> 6;                // rep X0 = w*4 + m
    const float yl = (float)l - 63.5f;

    float R[4][4], S[4][4];
    #pragma unroll
    for (int m = 0; m < 4; ++m)
        #pragma unroll
        for (int k = 0; k < 4; ++k) { R[m][k] = 0.f; S[m][k] = 0.f; }

    // acc += omf*f16(lo/hi of D0) + fr*f16(lo/hi of D1)
    #define MIXLO(ACC, WF, D) \
        asm("v_fma_mix_f32 %0, %1, %2, %0 op_sel:[0,0,0] op_sel_hi:[0,1,0]" \
            : "+v"(ACC) : "v"(WF), "v"(D))
    #define MIXHI(ACC, WF, D) \
        asm("v_fma_mix_f32 %0, %1, %2, %0 op_sel:[0,1,0] op_sel_hi:[0,1,0]" \
            : "+v"(ACC) : "v"(WF), "v"(D))

    #define SAMPLE4(U, RA, RB, SA, SB) do {                                   \
        int   ii  = (int)(U);                                                 \
        float fr  = __builtin_amdgcn_fractf(U);                               \
        float omf = 1.f - fr;                                                 \
        const uint2* pp = (const uint2*)(rowb + ii * 8);                      \
        uint2 d = pp[0];                                                      \
        uint2 e = pp[1];                                                      \
        MIXLO(RA, omf, d.x); MIXLO(RA, fr, e.x);                              \
        MIXLO(RB, omf, d.y); MIXLO(RB, fr, e.y);                              \
        MIXHI(SA, omf, d.y); MIXHI(SA, fr, e.y);                              \
        MIXHI(SB, omf, d.x); MIXHI(SB, fr, e.x);                              \
    } while (0)

    #pragma unroll 1
    for (int gi = 0; gi < 32; ++gi) {
        const int a = gi + 1;
        const float cs = s_cs[a];
        const float sn = s_sn[a];
        const float ay = fmaf(yl, sn, KBIAS);
        const float by = fmaf(yl, -cs, KBIAS);
        const char* rowb = (const char*)&s_rows[gi * GSTR * 2];
        #pragma unroll
        for (int m = 0; m < 4; ++m) {
            const float xr = (float)(w * 4 + m) - 63.5f;
            float uA = fmaf(xr, cs, ay);    // u_a(Q)
            float uB = fmaf(xr, sn, by);    // u_a(rQ)
            float uC = SMIR - uA;           // u_a(r2Q)
            float uD = SMIR - uB;           // u_a(r3Q)
            SAMPLE4(uA, R[m][0], R[m][1], S[m][0], S[m][3]);
            SAMPLE4(uB, R[m][1], R[m][2], S[m][3], S[m][2]);
            SAMPLE4(uC, R[m][2], R[m][3], S[m][2], S[m][1]);
            SAMPLE4(uD, R[m][3], R[m][0], S[m][1], S[m][0]);
        }
    }

    // special rows {0,64}: slot = f16x2 (row0, row64); one 8B read = both taps
    {
        const float by = fmaf(yl, -1.f, KBIAS);
        const char* spb = (const char*)s_sp;
        #define SAMPLE2(U, RA, RB) do {                                       \
            int   ii  = (int)(U);                                             \
            float fr  = __builtin_amdgcn_fractf(U);                           \
            float omf = 1.f - fr;                                             \
            const unsigned* qq = (const unsigned*)(spb + ii * 4);             \
            unsigned d0 = qq[0];                                              \
            unsigned d1 = qq[1];                                              \
            MIXLO(RA, omf, d0); MIXLO(RA, fr, d1);                            \
            MIXHI(RB, omf, d0); MIXHI(RB, fr, d1);                            \
        } while (0)
        #pragma unroll
        for (int m = 0; m < 4; ++m) {
            const float xr = (float)(w * 4 + m) - 63.5f;
            float uA = xr + KBIAS;
            float uB = by;
            float uC = SMIR - uA;
            float uD = SMIR - uB;
            SAMPLE2(uA, R[m][0], R[m][1]);
            SAMPLE2(uB, R[m][1], R[m][2]);
            SAMPLE2(uC, R[m][2], R[m][3]);
            SAMPLE2(uD, R[m][3], R[m][0]);
        }
        #undef SAMPLE2
    }
    #undef SAMPLE4
    #undef MIXLO
    #undef MIXHI

    // ---- fold mirror accs into owners: 4 LDS exchange rounds ----
    #pragma unroll
    for (int k = 0; k < 4; ++k) {
        __syncthreads();
        #pragma unroll
        for (int m = 0; m < 4; ++m)
            inbox[(l >> 2) * ISTR + (w * 4 + m) * 5 + (l & 3)] = S[m][k];
        __syncthreads();
        #pragma unroll
        for (int m = 0; m < 4; ++m)
            R[m][(k + 1) & 3] += inbox[w * ISTR + l * 5 + m];
    }

    // ---- write out: pixels r^k(Q_m), Q_m = (X0, l) ----
    float* ob = out + (size_t)blk * 16384;
    const float sc = (float)(M_PI / 128.0);
    #pragma unroll
    for (int m = 0; m < 4; ++m) {
        const int X0 = w * 4 + m;
        ob[X0 * 128 + l]                 = R[m][0] * sc;
        ob[(127 - l) * 128 + X0]         = R[m][1] * sc;
        ob[(127 - X0) * 128 + (127 - l)] = R[m][2] * sc;
        ob[l * 128 + (127 - X0)]         = R[m][3] * sc;
    }
}

extern "C" void kernel_launch(void* const* d_in, const int* in_sizes, int n_in,
                              void* d_out, int out_size, void* d_ws, size_t ws_size,
                              hipStream_t stream) {
    const float* F = (const float*)d_in[0];
    float* out = (float*)d_out;
    fbp_fused<<<1024, 1024, 0, stream>>>(F, out);
}